// Round 6
// baseline (8470.389 us; speedup 1.0000x reference)
//
#include <hip/hip_runtime.h>
#include <math.h>

#define Bsz 512
#define Nn  199
#define Ff  64
#define Uu  64
#define Hh  4
#define LDO 455   // Hh*Uu + Nn
#define NT  512   // threads per block (8 waves)
#define RPG 4     // rows per group
#define NG  50    // ceil(199/4) row-groups

typedef float f4_t __attribute__((ext_vector_type(4)));

// ---------------- prep: AW[h][n][m] = A[n][m] * W[h][n][m]; Abits[m][k] bitmask of A row m
__global__ __launch_bounds__(256)
void dgc_prep(const float* __restrict__ A, const float* __restrict__ W,
              float* __restrict__ AW, unsigned long long* __restrict__ Abits)
{
    int i = blockIdx.x * 256 + threadIdx.x;
    if (i < Hh * Nn * Nn) {
        int nm = i % (Nn * Nn);
        AW[i] = W[i] * A[nm];
    }
    if (i < Nn * 4) {
        int m = i >> 2, k = i & 3;
        unsigned long long bits = 0ull;
        #pragma unroll
        for (int l = 0; l < 64; ++l) {
            int j = k * 64 + l;
            if (j < Nn && A[m * Nn + j] != 0.0f) bits |= (1ull << l);
        }
        Abits[i] = bits;
    }
}

// ---------------- main fused kernel: one block per (b,h), 8 waves
__global__ __launch_bounds__(NT, 1)
void dgc_main(const float* __restrict__ X, const float* __restrict__ AW,
              const unsigned long long* __restrict__ AbitsG,
              const float* __restrict__ Kg, const float* __restrict__ Tg,
              const float* __restrict__ b1g, const float* __restrict__ b2g,
              float* __restrict__ out)
{
    // LDS: 51200 + 52000 + 16384 + 6400 + 26112 = 152096 B (< 160 KiB, 1 block/CU, 8 waves)
    __shared__ __align__(16) float Xs[Nn + 1][Ff];     // X_b, padded row 199 (zeroed)
    __shared__ __align__(16) float Ks[Ff + 1][200];    // kernel_h [f][j], pitch 200, pads zeroed
    __shared__ __align__(16) float Ts[Ff][Uu];         // T_h
    __shared__ unsigned long long Ab[200][4];          // adjacency row bitmasks
    __shared__ __align__(16) float sc[8][RPG][204];    // per-wave scratch: feat/mask/node rows

    const int tid  = threadIdx.x;
    const int lane = tid & 63;
    const int w    = __builtin_amdgcn_readfirstlane(tid >> 6);
    const int b    = blockIdx.x >> 2;
    const int h    = blockIdx.x & 3;

    // ---- stage X_b (coalesced float4): 199*64/4 = 3184 f4
    {
        const f4_t* src = (const f4_t*)(X + (size_t)b * Nn * Ff);
        f4_t* dst = (f4_t*)&Xs[0][0];
        #pragma unroll
        for (int it = 0; it < 7; ++it) {
            int idx = tid + it * NT;
            if (idx < Nn * Ff / 4) dst[idx] = src[idx];
        }
        if (tid < Ff) Xs[Nn][tid] = 0.0f;  // zero pad row (node-phase overread)
    }
    // ---- stage kernel_h into [f][j] pitch-200
    {
        const float* src = Kg + (size_t)h * Ff * Nn;
        for (int i = tid; i < Ff * Nn; i += NT) {
            int f = i / Nn, j = i - f * Nn;
            Ks[f][j] = src[i];
        }
        if (tid < Ff)  Ks[tid][199] = 0.0f;   // pad col
        if (tid < 200) Ks[Ff][tid]  = 0.0f;   // pad row (never hit by f-quad loop, but safe)
    }
    // ---- stage T_h: 4096 floats = 1024 f4
    {
        const f4_t* src = (const f4_t*)(Tg + (size_t)h * Ff * Uu);
        f4_t* dst = (f4_t*)&Ts[0][0];
        #pragma unroll
        for (int it = 0; it < 2; ++it) dst[tid + it * NT] = src[tid + it * NT];
    }
    // ---- stage adjacency bitmasks (796 u64) -- strided: 796 > NT
    for (int i = tid; i < Nn * 4; i += NT) ((unsigned long long*)Ab)[i] = AbitsG[i];

    // ---- per-thread bias registers
    float b1v[4];
    #pragma unroll
    for (int k = 0; k < 4; ++k) {
        int j = lane + 64 * k;
        b1v[k] = (j < Nn) ? b1g[h * Nn + j] : 0.0f;
    }
    const float b2v = b2g[h * Uu + lane];

    __syncthreads();

    const float* AWh  = AW + (size_t)h * Nn * Nn;
    float*       outb = out + (size_t)b * Nn * LDO;

    // 50 row-groups of 4 (last has 3), round-robined over the 8 waves; no barriers needed.
    for (int g = w; g < NG; g += 8) {
        const int m0 = __builtin_amdgcn_readfirstlane(g * RPG);
        const int R  = min(RPG, Nn - m0);   // wave-uniform

        // ---- Phase A: feat rows m0..m0+3 (lane = f). feat[m,f] = sum_n AW[n,m]*X[n,f]
        float fa[RPG];
        #pragma unroll
        for (int r = 0; r < RPG; ++r) fa[r] = 0.0f;
        #pragma unroll 4
        for (int n = 0; n < Nn; ++n) {
            float xv = Xs[n][lane];
            int base = __builtin_amdgcn_readfirstlane(n * Nn + m0);  // -> scalar loads of AW chunk
            #pragma unroll
            for (int r = 0; r < RPG; ++r) fa[r] = fmaf(AWh[base + r], xv, fa[r]);
        }
        #pragma unroll
        for (int r = 0; r < RPG; ++r) sc[w][r][lane] = fa[r];

        // ---- Phase B: dense tile, lane covers j = lane+64k, k<4; accumulate over f
        float d[RPG][4];
        #pragma unroll
        for (int r = 0; r < RPG; ++r)
            #pragma unroll
            for (int k = 0; k < 4; ++k) d[r][k] = 0.0f;
        for (int f = 0; f < Ff; f += 4) {
            f4_t fr[RPG];
            #pragma unroll
            for (int r = 0; r < RPG; ++r) fr[r] = *(const f4_t*)&sc[w][r][f];  // uniform b128
            float kv[4][4];
            #pragma unroll
            for (int df = 0; df < 4; ++df)
                #pragma unroll
                for (int k = 0; k < 4; ++k) kv[df][k] = Ks[f + df][lane + 64 * k];
            #pragma unroll
            for (int r = 0; r < RPG; ++r)
                #pragma unroll
                for (int df = 0; df < 4; ++df)
                    #pragma unroll
                    for (int k = 0; k < 4; ++k)
                        d[r][k] = fmaf(fr[r][df], kv[df][k], d[r][k]);
        }

        // ---- Phase C: masked softmax per row; write mask row to scratch (and h==3 slice to out)
        // FULLY UNROLLED over r (compile-time indices into d[][]) with a wave-uniform
        // if(r<R) guard — runtime-bounded `for(r<R)` put d[][] in scratch: 18.4 GB/dispatch
        // of spill traffic, VALUBusy 8% (R4 counters). Do not reintroduce.
        #pragma unroll
        for (int r = 0; r < RPG; ++r) {
            if (r < R) {
                int m = m0 + r;
                float lg[4]; bool val[4];
                #pragma unroll
                for (int k = 0; k < 4; ++k) {
                    unsigned long long ab = Ab[m][k];
                    int j = lane + 64 * k;
                    val[k] = (j < Nn) && ((ab >> lane) & 1ull);
                    lg[k]  = d[r][k] + b1v[k];
                }
                float mx = -INFINITY;
                #pragma unroll
                for (int k = 0; k < 4; ++k) if (val[k]) mx = fmaxf(mx, lg[k]);
                #pragma unroll
                for (int off = 32; off; off >>= 1) mx = fmaxf(mx, __shfl_xor(mx, off, 64));
                float e[4], s = 0.0f;
                #pragma unroll
                for (int k = 0; k < 4; ++k) {
                    e[k] = val[k] ? expf(lg[k] - mx) : 0.0f;  // masked -> exactly 0, as reference
                    s += e[k];
                }
                #pragma unroll
                for (int off = 32; off; off >>= 1) s += __shfl_xor(s, off, 64);
                float inv = 1.0f / s;
                #pragma unroll
                for (int k = 0; k < 4; ++k) {
                    float mv = e[k] * inv;
                    int j = lane + 64 * k;
                    if (j < 200) sc[w][r][j] = mv;                       // cols 0..199 (199 stays 0)
                    if (h == 3 && j < Nn) outb[m * LDO + 256 + j] = mv;  // last head's mask
                }
            }
        }

        // ---- Phase D: node rows (lane = f). node[m,f] = sum_j mask[m,j]*X[j,f]
        float nd[RPG];
        #pragma unroll
        for (int r = 0; r < RPG; ++r) nd[r] = 0.0f;
        for (int j = 0; j < 200; j += 4) {
            float xv[4];
            #pragma unroll
            for (int dj = 0; dj < 4; ++dj) xv[dj] = Xs[j + dj][lane];
            #pragma unroll
            for (int r = 0; r < RPG; ++r) {
                f4_t mv = *(const f4_t*)&sc[w][r][j];  // uniform b128
                #pragma unroll
                for (int dj = 0; dj < 4; ++dj) nd[r] = fmaf(mv[dj], xv[dj], nd[r]);
            }
        }

        // ---- Phase E: out rows (lane = u). out[m,u] = bias2[u] + sum_f node[m,f]*T[f,u]
        #pragma unroll
        for (int r = 0; r < RPG; ++r) sc[w][r][lane] = nd[r];  // node rows -> scratch (mask consumed)
        float o[RPG];
        #pragma unroll
        for (int r = 0; r < RPG; ++r) o[r] = b2v;
        for (int f = 0; f < Ff; f += 4) {
            float tv[4];
            #pragma unroll
            for (int df = 0; df < 4; ++df) tv[df] = Ts[f + df][lane];
            #pragma unroll
            for (int r = 0; r < RPG; ++r) {
                f4_t nv = *(const f4_t*)&sc[w][r][f];  // uniform b128
                #pragma unroll
                for (int df = 0; df < 4; ++df) o[r] = fmaf(nv[df], tv[df], o[r]);
            }
        }
        #pragma unroll
        for (int r = 0; r < RPG; ++r) {
            int m = m0 + r;
            if (m < Nn) outb[m * LDO + h * 64 + lane] = o[r];
        }
    }
}

extern "C" void kernel_launch(void* const* d_in, const int* in_sizes, int n_in,
                              void* d_out, int out_size, void* d_ws, size_t ws_size,
                              hipStream_t stream)
{
    const float* X  = (const float*)d_in[0];
    const float* A  = (const float*)d_in[1];
    const float* W  = (const float*)d_in[2];
    const float* Kg = (const float*)d_in[3];
    const float* Tg = (const float*)d_in[4];
    const float* b1 = (const float*)d_in[5];
    const float* b2 = (const float*)d_in[6];
    float* out = (float*)d_out;

    float* AW = (float*)d_ws;                                                 // 158404 floats
    unsigned long long* Abits = (unsigned long long*)((char*)d_ws + 633616);  // 796 u64

    dgc_prep<<<dim3((Hh * Nn * Nn + 255) / 256), dim3(256), 0, stream>>>(A, W, AW, Abits);
    dgc_main<<<dim3(Bsz * Hh), dim3(NT), 0, stream>>>(X, AW, Abits, Kg, Tg, b1, b2, out);
}

// Round 8
// 4002.423 us; speedup vs baseline: 2.1163x; 2.1163x over previous
//
#include <hip/hip_runtime.h>
#include <math.h>

#define Bsz 512
#define Nn  199
#define Ff  64
#define Uu  64
#define Hh  4
#define LDO 455   // Hh*Uu + Nn
#define NT  512   // threads per block (8 waves)
#define RPG 4     // rows per group
#define NG  50    // ceil(199/4) row-groups

typedef float f4_t __attribute__((ext_vector_type(4)));

// ---------------- prep: AW[h][n][m] = A[n][m] * W[h][n][m]; Abits[m][k] bitmask of A row m
__global__ __launch_bounds__(256)
void dgc_prep(const float* __restrict__ A, const float* __restrict__ W,
              float* __restrict__ AW, unsigned long long* __restrict__ Abits)
{
    int i = blockIdx.x * 256 + threadIdx.x;
    if (i < Hh * Nn * Nn) {
        int nm = i % (Nn * Nn);
        AW[i] = W[i] * A[nm];
    }
    if (i < Nn * 4) {
        int m = i >> 2, k = i & 3;
        unsigned long long bits = 0ull;
        #pragma unroll
        for (int l = 0; l < 64; ++l) {
            int j = k * 64 + l;
            if (j < Nn && A[m * Nn + j] != 0.0f) bits |= (1ull << l);
        }
        Abits[i] = bits;
    }
}

// ---------------- main fused kernel: one block per (b,h), 8 waves
// NOTE (R6 post-mortem): per-thread ARRAYS (float d[4][4] etc.) were kept in
// scratch by the compiler even with static post-unroll indices -> 18+ GB/dispatch
// of private RMW traffic, VALUBusy 8%. This version has ZERO local aggregates:
// named f4_t vectors / named scalars only. Do not reintroduce arrays here.
__global__ __launch_bounds__(NT, 1)
void dgc_main(const float* __restrict__ X, const float* __restrict__ AW,
              const unsigned long long* __restrict__ AbitsG,
              const float* __restrict__ Kg, const float* __restrict__ Tg,
              const float* __restrict__ b1g, const float* __restrict__ b2g,
              float* __restrict__ out)
{
    // LDS: 51200 + 52000 + 16384 + 6400 + 26112 = 152096 B (< 160 KiB, 1 block/CU, 8 waves)
    __shared__ __align__(16) float Xs[Nn + 1][Ff];     // X_b, padded row 199 (zeroed)
    __shared__ __align__(16) float Ks[Ff + 1][200];    // kernel_h [f][j], pitch 200, pads zeroed
    __shared__ __align__(16) float Ts[Ff][Uu];         // T_h
    __shared__ unsigned long long Ab[200][4];          // adjacency row bitmasks
    __shared__ __align__(16) float sc[8][RPG][204];    // per-wave scratch: feat/mask/node rows

    const int tid  = threadIdx.x;
    const int lane = tid & 63;
    const int w    = __builtin_amdgcn_readfirstlane(tid >> 6);
    const int b    = blockIdx.x >> 2;
    const int h    = blockIdx.x & 3;

    // ---- stage X_b (coalesced float4): 199*64/4 = 3184 f4
    {
        const f4_t* src = (const f4_t*)(X + (size_t)b * Nn * Ff);
        f4_t* dst = (f4_t*)&Xs[0][0];
        #pragma unroll
        for (int it = 0; it < 7; ++it) {
            int idx = tid + it * NT;
            if (idx < Nn * Ff / 4) dst[idx] = src[idx];
        }
        if (tid < Ff) Xs[Nn][tid] = 0.0f;  // zero pad row (node-phase overread)
    }
    // ---- stage kernel_h into [f][j] pitch-200
    {
        const float* src = Kg + (size_t)h * Ff * Nn;
        for (int i = tid; i < Ff * Nn; i += NT) {
            int f = i / Nn, j = i - f * Nn;
            Ks[f][j] = src[i];
        }
        if (tid < Ff)  Ks[tid][199] = 0.0f;   // pad col
        if (tid < 200) Ks[Ff][tid]  = 0.0f;   // pad row (never hit by f-quad loop, but safe)
    }
    // ---- stage T_h: 4096 floats = 1024 f4
    {
        const f4_t* src = (const f4_t*)(Tg + (size_t)h * Ff * Uu);
        f4_t* dst = (f4_t*)&Ts[0][0];
        #pragma unroll
        for (int it = 0; it < 2; ++it) dst[tid + it * NT] = src[tid + it * NT];
    }
    // ---- stage adjacency bitmasks (796 u64) -- strided: 796 > NT
    for (int i = tid; i < Nn * 4; i += NT) ((unsigned long long*)Ab)[i] = AbitsG[i];

    // ---- per-thread bias registers (named scalars -> vector)
    const float b1x = (lane       < Nn) ? b1g[h * Nn + lane      ] : 0.0f;
    const float b1y = (lane + 64  < Nn) ? b1g[h * Nn + lane + 64 ] : 0.0f;
    const float b1z = (lane + 128 < Nn) ? b1g[h * Nn + lane + 128] : 0.0f;
    const float b1w = (lane + 192 < Nn) ? b1g[h * Nn + lane + 192] : 0.0f;
    const f4_t  b1vec = { b1x, b1y, b1z, b1w };
    const float b2v = b2g[h * Uu + lane];

    __syncthreads();

    const float* AWh  = AW + (size_t)h * Nn * Nn;
    float*       outb = out + (size_t)b * Nn * LDO;

    // 50 row-groups of 4 (last has 3), round-robined over the 8 waves; no barriers needed.
    for (int g = w; g < NG; g += 8) {
        const int m0 = __builtin_amdgcn_readfirstlane(g * RPG);
        const int R  = min(RPG, Nn - m0);   // wave-uniform

        // ---- Phase A: feat rows m0..m0+3 (lane = f). feat[m,f] = sum_n AW[n,m]*X[n,f]
        // fav components = row index r. AW loads are wave-uniform -> scalar loads.
        f4_t fav = { 0.0f, 0.0f, 0.0f, 0.0f };
        for (int n = 0; n < Nn; ++n) {
            float xv = Xs[n][lane];
            int base = __builtin_amdgcn_readfirstlane(n * Nn + m0);
            f4_t aw = { AWh[base], AWh[base + 1], AWh[base + 2], AWh[base + 3] };
            fav += aw * xv;
        }
        sc[w][0][lane] = fav.x;
        sc[w][1][lane] = fav.y;
        sc[w][2][lane] = fav.z;
        sc[w][3][lane] = fav.w;

        // ---- Phase B: dense tile. Row vectors d0v..d3v, components k (j = lane+64k).
        f4_t d0v = { 0.0f, 0.0f, 0.0f, 0.0f };
        f4_t d1v = { 0.0f, 0.0f, 0.0f, 0.0f };
        f4_t d2v = { 0.0f, 0.0f, 0.0f, 0.0f };
        f4_t d3v = { 0.0f, 0.0f, 0.0f, 0.0f };
        for (int f = 0; f < Ff; f += 4) {
            f4_t f0 = *(const f4_t*)&sc[w][0][f];   // uniform b128 (feat row 0, f..f+3)
            f4_t f1 = *(const f4_t*)&sc[w][1][f];
            f4_t f2 = *(const f4_t*)&sc[w][2][f];
            f4_t f3 = *(const f4_t*)&sc[w][3][f];
            f4_t k0 = { Ks[f    ][lane], Ks[f    ][lane + 64], Ks[f    ][lane + 128], Ks[f    ][lane + 192] };
            f4_t k1 = { Ks[f + 1][lane], Ks[f + 1][lane + 64], Ks[f + 1][lane + 128], Ks[f + 1][lane + 192] };
            f4_t k2 = { Ks[f + 2][lane], Ks[f + 2][lane + 64], Ks[f + 2][lane + 128], Ks[f + 2][lane + 192] };
            f4_t k3 = { Ks[f + 3][lane], Ks[f + 3][lane + 64], Ks[f + 3][lane + 128], Ks[f + 3][lane + 192] };
            d0v += f0.x * k0; d0v += f0.y * k1; d0v += f0.z * k2; d0v += f0.w * k3;
            d1v += f1.x * k0; d1v += f1.y * k1; d1v += f1.z * k2; d1v += f1.w * k3;
            d2v += f2.x * k0; d2v += f2.y * k1; d2v += f2.z * k2; d2v += f2.w * k3;
            d3v += f3.x * k0; d3v += f3.y * k1; d3v += f3.z * k2; d3v += f3.w * k3;
        }

        // ---- Phase C: masked softmax per row (named scalars only; wave-uniform guard)
#define DGC_SMROW(RIDX, DV)                                                          \
        if (RIDX < R) {                                                              \
            const int m_ = m0 + RIDX;                                                \
            f4_t lg = DV + b1vec;                                                    \
            unsigned long long a0 = Ab[m_][0], a1 = Ab[m_][1];                       \
            unsigned long long a2 = Ab[m_][2], a3 = Ab[m_][3];                       \
            bool v0 = (a0 >> lane) & 1ull, v1 = (a1 >> lane) & 1ull;                 \
            bool v2 = (a2 >> lane) & 1ull, v3 = (a3 >> lane) & 1ull;                 \
            float mx = fmaxf(fmaxf(v0 ? lg.x : -1e30f, v1 ? lg.y : -1e30f),          \
                             fmaxf(v2 ? lg.z : -1e30f, v3 ? lg.w : -1e30f));         \
            for (int off = 32; off; off >>= 1) mx = fmaxf(mx, __shfl_xor(mx, off, 64)); \
            float e0 = v0 ? expf(lg.x - mx) : 0.0f;                                  \
            float e1 = v1 ? expf(lg.y - mx) : 0.0f;                                  \
            float e2 = v2 ? expf(lg.z - mx) : 0.0f;                                  \
            float e3 = v3 ? expf(lg.w - mx) : 0.0f;                                  \
            float s = e0 + e1 + e2 + e3;                                             \
            for (int off = 32; off; off >>= 1) s += __shfl_xor(s, off, 64);          \
            float inv = 1.0f / s;                                                    \
            float q0 = e0 * inv, q1 = e1 * inv, q2 = e2 * inv, q3 = e3 * inv;        \
            sc[w][RIDX][lane]       = q0;                                            \
            sc[w][RIDX][lane + 64]  = q1;                                            \
            sc[w][RIDX][lane + 128] = q2;                                            \
            if (lane < 8) sc[w][RIDX][lane + 192] = q3;  /* col 199 gets 0 */        \
            if (h == 3) {                                                            \
                outb[m_ * LDO + 256 + lane]       = q0;                              \
                outb[m_ * LDO + 256 + lane + 64]  = q1;                              \
                outb[m_ * LDO + 256 + lane + 128] = q2;                              \
                if (lane < 7) outb[m_ * LDO + 256 + lane + 192] = q3;                \
            }                                                                        \
        }
        DGC_SMROW(0, d0v)
        DGC_SMROW(1, d1v)
        DGC_SMROW(2, d2v)
        DGC_SMROW(3, d3v)
#undef DGC_SMROW

        // ---- Phase D: node rows (lane = f). node[m,f] = sum_j mask[m,j]*X[j,f]
        float nd0 = 0.0f, nd1 = 0.0f, nd2 = 0.0f, nd3 = 0.0f;
        for (int j = 0; j < 200; j += 4) {
            float x0 = Xs[j][lane], x1 = Xs[j + 1][lane];
            float x2 = Xs[j + 2][lane], x3 = Xs[j + 3][lane];
            f4_t q0 = *(const f4_t*)&sc[w][0][j];   // uniform b128 (mask row 0)
            f4_t q1 = *(const f4_t*)&sc[w][1][j];
            f4_t q2 = *(const f4_t*)&sc[w][2][j];
            f4_t q3 = *(const f4_t*)&sc[w][3][j];
            nd0 = fmaf(q0.x, x0, fmaf(q0.y, x1, fmaf(q0.z, x2, fmaf(q0.w, x3, nd0))));
            nd1 = fmaf(q1.x, x0, fmaf(q1.y, x1, fmaf(q1.z, x2, fmaf(q1.w, x3, nd1))));
            nd2 = fmaf(q2.x, x0, fmaf(q2.y, x1, fmaf(q2.z, x2, fmaf(q2.w, x3, nd2))));
            nd3 = fmaf(q3.x, x0, fmaf(q3.y, x1, fmaf(q3.z, x2, fmaf(q3.w, x3, nd3))));
        }

        // ---- Phase E: out rows (lane = u). out[m,u] = bias2[u] + sum_f node[m,f]*T[f,u]
        sc[w][0][lane] = nd0;   // node rows -> scratch (mask consumed)
        sc[w][1][lane] = nd1;
        sc[w][2][lane] = nd2;
        sc[w][3][lane] = nd3;
        float o0 = b2v, o1 = b2v, o2 = b2v, o3 = b2v;
        for (int f = 0; f < Ff; f += 4) {
            float t0 = Ts[f][lane], t1 = Ts[f + 1][lane];
            float t2 = Ts[f + 2][lane], t3 = Ts[f + 3][lane];
            f4_t q0 = *(const f4_t*)&sc[w][0][f];   // uniform b128 (node row 0)
            f4_t q1 = *(const f4_t*)&sc[w][1][f];
            f4_t q2 = *(const f4_t*)&sc[w][2][f];
            f4_t q3 = *(const f4_t*)&sc[w][3][f];
            o0 = fmaf(q0.x, t0, fmaf(q0.y, t1, fmaf(q0.z, t2, fmaf(q0.w, t3, o0))));
            o1 = fmaf(q1.x, t0, fmaf(q1.y, t1, fmaf(q1.z, t2, fmaf(q1.w, t3, o1))));
            o2 = fmaf(q2.x, t0, fmaf(q2.y, t1, fmaf(q2.z, t2, fmaf(q2.w, t3, o2))));
            o3 = fmaf(q3.x, t0, fmaf(q3.y, t1, fmaf(q3.z, t2, fmaf(q3.w, t3, o3))));
        }
        if (m0     < Nn) outb[(m0    ) * LDO + h * 64 + lane] = o0;
        if (m0 + 1 < Nn) outb[(m0 + 1) * LDO + h * 64 + lane] = o1;
        if (m0 + 2 < Nn) outb[(m0 + 2) * LDO + h * 64 + lane] = o2;
        if (m0 + 3 < Nn) outb[(m0 + 3) * LDO + h * 64 + lane] = o3;
    }
}

extern "C" void kernel_launch(void* const* d_in, const int* in_sizes, int n_in,
                              void* d_out, int out_size, void* d_ws, size_t ws_size,
                              hipStream_t stream)
{
    const float* X  = (const float*)d_in[0];
    const float* A  = (const float*)d_in[1];
    const float* W  = (const float*)d_in[2];
    const float* Kg = (const float*)d_in[3];
    const float* Tg = (const float*)d_in[4];
    const float* b1 = (const float*)d_in[5];
    const float* b2 = (const float*)d_in[6];
    float* out = (float*)d_out;

    float* AW = (float*)d_ws;                                                 // 158404 floats
    unsigned long long* Abits = (unsigned long long*)((char*)d_ws + 633616);  // 796 u64

    dgc_prep<<<dim3((Hh * Nn * Nn + 255) / 256), dim3(256), 0, stream>>>(A, W, AW, Abits);
    dgc_main<<<dim3(Bsz * Hh), dim3(NT), 0, stream>>>(X, AW, Abits, Kg, Tg, b1, b2, out);
}

// Round 9
// 2826.421 us; speedup vs baseline: 2.9969x; 1.4161x over previous
//
#include <hip/hip_runtime.h>
#include <math.h>

#define Bsz 512
#define Nn  199
#define Ff  64
#define Uu  64
#define Hh  4
#define LDO 455   // Hh*Uu + Nn
#define NT  512   // threads per block (8 waves)
#define RPG 8     // rows per group (R8: was 4; amortizes Ks/Xs streams over 2x rows)
#define NG  25    // ceil(199/8) row-groups

typedef float f4_t __attribute__((ext_vector_type(4)));

// ---------------- prep: AW[h][n][m] = A[n][m] * W[h][n][m]; Abits[m][k] bitmask of A row m
__global__ __launch_bounds__(256)
void dgc_prep(const float* __restrict__ A, const float* __restrict__ W,
              float* __restrict__ AW, unsigned long long* __restrict__ Abits)
{
    int i = blockIdx.x * 256 + threadIdx.x;
    if (i < Hh * Nn * Nn) {
        int nm = i % (Nn * Nn);
        AW[i] = W[i] * A[nm];
    }
    if (i < Nn * 4) {
        int m = i >> 2, k = i & 3;
        unsigned long long bits = 0ull;
        #pragma unroll
        for (int l = 0; l < 64; ++l) {
            int j = k * 64 + l;
            if (j < Nn && A[m * Nn + j] != 0.0f) bits |= (1ull << l);
        }
        Abits[i] = bits;
    }
}

// ---------------- main fused kernel: one block per (b,h), 8 waves
// R6 lesson: NO local aggregates (arrays -> scratch, 18 GB/dispatch). Named vectors only.
// R8 lesson: DS-pipe-bound (VALUBusy 16%, DS est ~2x VALU). RPG=8 amortizes the
// shared operand streams; Ts evicted to global (L2) to keep LDS <= 160K.
__global__ __launch_bounds__(NT, 1)
void dgc_main(const float* __restrict__ X, const float* __restrict__ AW,
              const unsigned long long* __restrict__ AbitsG,
              const float* __restrict__ Kg, const float* __restrict__ Tg,
              const float* __restrict__ b1g, const float* __restrict__ b2g,
              float* __restrict__ out)
{
    // LDS: 51200 (Xs) + 52224 (Ks) + 6400 (Ab) + 51200 (sc) = 161024 B <= 163840
    __shared__ __align__(16) float Xs[Nn + 1][Ff];     // X_b, padded row 199 (zeroed)
    __shared__ __align__(16) float Ks[Ff][204];        // kernel_h [f][j]; cols>=199 junk (reads discarded)
    __shared__ unsigned long long Ab[200][4];          // adjacency row bitmasks
    __shared__ __align__(16) float sc[8][RPG][200];    // per-wave scratch: feat/mask/node rows

    const int tid  = threadIdx.x;
    const int lane = tid & 63;
    const int w    = __builtin_amdgcn_readfirstlane(tid >> 6);
    // h-major decode: the 4 head-blocks of one b are 512 apart -> same XCD slot (mod 8),
    // so all writers of a given output row share one L2 (targets WRITE churn).
    const int b    = blockIdx.x & 511;
    const int h    = blockIdx.x >> 9;

    // ---- stage X_b (coalesced float4): 199*64/4 = 3184 f4
    {
        const f4_t* src = (const f4_t*)(X + (size_t)b * Nn * Ff);
        f4_t* dst = (f4_t*)&Xs[0][0];
        #pragma unroll
        for (int it = 0; it < 7; ++it) {
            int idx = tid + it * NT;
            if (idx < Nn * Ff / 4) dst[idx] = src[idx];
        }
        if (tid < Ff) Xs[Nn][tid] = 0.0f;  // zero pad row (node-phase overread)
    }
    // ---- stage kernel_h into [f][j] pitch-204
    {
        const float* src = Kg + (size_t)h * Ff * Nn;
        for (int i = tid; i < Ff * Nn; i += NT) {
            int f = i / Nn, j = i - f * Nn;
            Ks[f][j] = src[i];
        }
        if (tid < Ff) Ks[tid][199] = 0.0f;   // col 199 = 0 (j=199 guarded anyway)
    }
    // ---- stage adjacency bitmasks (796 u64) -- strided: 796 > NT
    for (int i = tid; i < Nn * 4; i += NT) ((unsigned long long*)Ab)[i] = AbitsG[i];

    // ---- per-thread bias registers (named scalars -> vector)
    const float b1x = (lane       < Nn) ? b1g[h * Nn + lane      ] : 0.0f;
    const float b1y = (lane + 64  < Nn) ? b1g[h * Nn + lane + 64 ] : 0.0f;
    const float b1z = (lane + 128 < Nn) ? b1g[h * Nn + lane + 128] : 0.0f;
    const float b1w = (lane + 192 < Nn) ? b1g[h * Nn + lane + 192] : 0.0f;
    const f4_t  b1vec = { b1x, b1y, b1z, b1w };
    const float b2v = b2g[h * Uu + lane];

    __syncthreads();

    const float* AWh  = AW + (size_t)h * Nn * Nn;
    const float* Th   = Tg + (size_t)h * Ff * Uu;
    float*       outb = out + (size_t)b * Nn * LDO;

    // 25 row-groups of 8 (last has 7), round-robined over the 8 waves; no barriers needed.
    for (int g = w; g < NG; g += 8) {
        const int m0 = __builtin_amdgcn_readfirstlane(g * RPG);
        const int R  = min(RPG, Nn - m0);   // wave-uniform

        // ---- Phase A: feat rows m0..m0+7 (lane = f). feat[m,f] = sum_n AW[n,m]*X[n,f]
        f4_t fav0 = { 0.0f, 0.0f, 0.0f, 0.0f };
        f4_t fav1 = { 0.0f, 0.0f, 0.0f, 0.0f };
        #pragma unroll 4
        for (int n = 0; n < Nn; ++n) {
            float xv = Xs[n][lane];
            int base = __builtin_amdgcn_readfirstlane(n * Nn + m0);  // -> scalar loads
            f4_t aw0 = { AWh[base    ], AWh[base + 1], AWh[base + 2], AWh[base + 3] };
            f4_t aw1 = { AWh[base + 4], AWh[base + 5], AWh[base + 6], AWh[base + 7] };
            fav0 += aw0 * xv;
            fav1 += aw1 * xv;
        }
        sc[w][0][lane] = fav0.x;  sc[w][1][lane] = fav0.y;
        sc[w][2][lane] = fav0.z;  sc[w][3][lane] = fav0.w;
        sc[w][4][lane] = fav1.x;  sc[w][5][lane] = fav1.y;
        sc[w][6][lane] = fav1.z;  sc[w][7][lane] = fav1.w;

        // ---- Phase B: dense tile. Row vectors d0v..d7v, components k (j = lane+64k).
        f4_t d0v = {0,0,0,0}, d1v = {0,0,0,0}, d2v = {0,0,0,0}, d3v = {0,0,0,0};
        f4_t d4v = {0,0,0,0}, d5v = {0,0,0,0}, d6v = {0,0,0,0}, d7v = {0,0,0,0};
        for (int f = 0; f < Ff; f += 4) {
            // Ks lane reads shared by all 8 rows (the RPG amortization)
            f4_t k0 = { Ks[f    ][lane], Ks[f    ][lane + 64], Ks[f    ][lane + 128], Ks[f    ][lane + 192] };
            f4_t k1 = { Ks[f + 1][lane], Ks[f + 1][lane + 64], Ks[f + 1][lane + 128], Ks[f + 1][lane + 192] };
            f4_t k2 = { Ks[f + 2][lane], Ks[f + 2][lane + 64], Ks[f + 2][lane + 128], Ks[f + 2][lane + 192] };
            f4_t k3 = { Ks[f + 3][lane], Ks[f + 3][lane + 64], Ks[f + 3][lane + 128], Ks[f + 3][lane + 192] };
            f4_t fr;
#define DGC_BROW(R_, DV)                                                  \
            fr = *(const f4_t*)&sc[w][R_][f];  /* uniform b128 bcast */   \
            DV += fr.x * k0; DV += fr.y * k1; DV += fr.z * k2; DV += fr.w * k3;
            DGC_BROW(0, d0v)  DGC_BROW(1, d1v)  DGC_BROW(2, d2v)  DGC_BROW(3, d3v)
            DGC_BROW(4, d4v)  DGC_BROW(5, d5v)  DGC_BROW(6, d6v)  DGC_BROW(7, d7v)
#undef DGC_BROW
        }

        // ---- Phase C: masked softmax per row (named scalars only; wave-uniform guard)
#define DGC_SMROW(RIDX, DV)                                                          \
        if (RIDX < R) {                                                              \
            const int m_ = m0 + RIDX;                                                \
            f4_t lg = DV + b1vec;                                                    \
            unsigned long long a0 = Ab[m_][0], a1 = Ab[m_][1];                       \
            unsigned long long a2 = Ab[m_][2], a3 = Ab[m_][3];                       \
            bool v0 = (a0 >> lane) & 1ull, v1 = (a1 >> lane) & 1ull;                 \
            bool v2 = (a2 >> lane) & 1ull, v3 = (a3 >> lane) & 1ull;                 \
            float mx = fmaxf(fmaxf(v0 ? lg.x : -1e30f, v1 ? lg.y : -1e30f),          \
                             fmaxf(v2 ? lg.z : -1e30f, v3 ? lg.w : -1e30f));         \
            for (int off = 32; off; off >>= 1) mx = fmaxf(mx, __shfl_xor(mx, off, 64)); \
            float e0 = v0 ? expf(lg.x - mx) : 0.0f;                                  \
            float e1 = v1 ? expf(lg.y - mx) : 0.0f;                                  \
            float e2 = v2 ? expf(lg.z - mx) : 0.0f;                                  \
            float e3 = v3 ? expf(lg.w - mx) : 0.0f;                                  \
            float s = e0 + e1 + e2 + e3;                                             \
            for (int off = 32; off; off >>= 1) s += __shfl_xor(s, off, 64);          \
            float inv = 1.0f / s;                                                    \
            float q0 = e0 * inv, q1 = e1 * inv, q2 = e2 * inv, q3 = e3 * inv;        \
            sc[w][RIDX][lane]       = q0;                                            \
            sc[w][RIDX][lane + 64]  = q1;                                            \
            sc[w][RIDX][lane + 128] = q2;                                            \
            if (lane < 8) sc[w][RIDX][lane + 192] = q3;  /* col 199 gets 0 */        \
            if (h == 3) {                                                            \
                outb[m_ * LDO + 256 + lane]       = q0;                              \
                outb[m_ * LDO + 256 + lane + 64]  = q1;                              \
                outb[m_ * LDO + 256 + lane + 128] = q2;                              \
                if (lane < 7) outb[m_ * LDO + 256 + lane + 192] = q3;                \
            }                                                                        \
        }
        DGC_SMROW(0, d0v)  DGC_SMROW(1, d1v)  DGC_SMROW(2, d2v)  DGC_SMROW(3, d3v)
        DGC_SMROW(4, d4v)  DGC_SMROW(5, d5v)  DGC_SMROW(6, d6v)  DGC_SMROW(7, d7v)
#undef DGC_SMROW

        // ---- Phase D: node rows (lane = f). node[m,f] = sum_j mask[m,j]*X[j,f]
        float nd0 = 0.0f, nd1 = 0.0f, nd2 = 0.0f, nd3 = 0.0f;
        float nd4 = 0.0f, nd5 = 0.0f, nd6 = 0.0f, nd7 = 0.0f;
        for (int j = 0; j < 200; j += 4) {
            // Xs lane reads shared by all 8 rows
            float x0 = Xs[j][lane], x1 = Xs[j + 1][lane];
            float x2 = Xs[j + 2][lane], x3 = Xs[j + 3][lane];
            f4_t q;
#define DGC_DROW(R_, ND)                                                  \
            q = *(const f4_t*)&sc[w][R_][j];  /* uniform b128 bcast */    \
            ND = fmaf(q.x, x0, fmaf(q.y, x1, fmaf(q.z, x2, fmaf(q.w, x3, ND))));
            DGC_DROW(0, nd0)  DGC_DROW(1, nd1)  DGC_DROW(2, nd2)  DGC_DROW(3, nd3)
            DGC_DROW(4, nd4)  DGC_DROW(5, nd5)  DGC_DROW(6, nd6)  DGC_DROW(7, nd7)
#undef DGC_DROW
        }

        // ---- Phase E: out rows (lane = u). out[m,u] = bias2[u] + sum_f node[m,f]*T[f,u]
        sc[w][0][lane] = nd0;  sc[w][1][lane] = nd1;
        sc[w][2][lane] = nd2;  sc[w][3][lane] = nd3;
        sc[w][4][lane] = nd4;  sc[w][5][lane] = nd5;
        sc[w][6][lane] = nd6;  sc[w][7][lane] = nd7;
        float o0 = b2v, o1 = b2v, o2 = b2v, o3 = b2v;
        float o4 = b2v, o5 = b2v, o6 = b2v, o7 = b2v;
        for (int f = 0; f < Ff; f += 4) {
            // T from global (L2-resident; off the DS pipe)
            const float* tp = Th + f * Uu + lane;
            float t0 = tp[0], t1 = tp[64], t2 = tp[128], t3 = tp[192];
            f4_t q;
#define DGC_EROW(R_, O_)                                                  \
            q = *(const f4_t*)&sc[w][R_][f];  /* uniform b128 bcast */    \
            O_ = fmaf(q.x, t0, fmaf(q.y, t1, fmaf(q.z, t2, fmaf(q.w, t3, O_))));
            DGC_EROW(0, o0)  DGC_EROW(1, o1)  DGC_EROW(2, o2)  DGC_EROW(3, o3)
            DGC_EROW(4, o4)  DGC_EROW(5, o5)  DGC_EROW(6, o6)  DGC_EROW(7, o7)
#undef DGC_EROW
        }
        if (m0     < Nn) outb[(m0    ) * LDO + h * 64 + lane] = o0;
        if (m0 + 1 < Nn) outb[(m0 + 1) * LDO + h * 64 + lane] = o1;
        if (m0 + 2 < Nn) outb[(m0 + 2) * LDO + h * 64 + lane] = o2;
        if (m0 + 3 < Nn) outb[(m0 + 3) * LDO + h * 64 + lane] = o3;
        if (m0 + 4 < Nn) outb[(m0 + 4) * LDO + h * 64 + lane] = o4;
        if (m0 + 5 < Nn) outb[(m0 + 5) * LDO + h * 64 + lane] = o5;
        if (m0 + 6 < Nn) outb[(m0 + 6) * LDO + h * 64 + lane] = o6;
        if (m0 + 7 < Nn) outb[(m0 + 7) * LDO + h * 64 + lane] = o7;
    }
}

extern "C" void kernel_launch(void* const* d_in, const int* in_sizes, int n_in,
                              void* d_out, int out_size, void* d_ws, size_t ws_size,
                              hipStream_t stream)
{
    const float* X  = (const float*)d_in[0];
    const float* A  = (const float*)d_in[1];
    const float* W  = (const float*)d_in[2];
    const float* Kg = (const float*)d_in[3];
    const float* Tg = (const float*)d_in[4];
    const float* b1 = (const float*)d_in[5];
    const float* b2 = (const float*)d_in[6];
    float* out = (float*)d_out;

    float* AW = (float*)d_ws;                                                 // 158404 floats
    unsigned long long* Abits = (unsigned long long*)((char*)d_ws + 633616);  // 796 u64

    dgc_prep<<<dim3((Hh * Nn * Nn + 255) / 256), dim3(256), 0, stream>>>(A, W, AW, Abits);
    dgc_main<<<dim3(Bsz * Hh), dim3(NT), 0, stream>>>(X, AW, Abits, Kg, Tg, b1, b2, out);
}